// Round 15
// baseline (3440.364 us; speedup 1.0000x reference)
//
#include <hip/hip_runtime.h>

constexpr int BB = 64, TT = 512, DD = 512, HH = 512;
constexpr int GG = 4 * HH;          // 2048 gate cols
constexpr int KK = DD + HH;         // 1024 fused K
constexpr int NBLK = 128, NTHR = 512;
// LDS: smx[8][1024B] swz | smh[8][1024B] swz | zl[16][129] f32 | mask[8][16]
constexpr int LDS_ZL = 16 * 129 * 4;
constexpr int LDS_BYTES = 8192 + 8192 + LDS_ZL + 512;

using short8 = __attribute__((ext_vector_type(8))) short;
using f32x4  = __attribute__((ext_vector_type(4))) float;

__device__ __host__ __forceinline__ unsigned short f2bf(float f) {
    union { float f; unsigned u; } v; v.f = f;
    unsigned u = v.u + 0x7fffu + ((v.u >> 16) & 1u);   // RNE
    return (unsigned short)(u >> 16);
}
__device__ __forceinline__ float fsig(float x) {
    return 1.f / (1.f + __expf(-x));
}
__device__ __forceinline__ float ftanh_(float x) {
    float e = __expf(2.f * fabsf(x));
    float r = 1.f - 2.f / (e + 1.f);
    return copysignf(r, x);
}

// ws: WB[2048][1024] bf16 (4MB) | hbuf[8 grp][2][8][256] u32 (128KB)
//     | flags[8 grp][16 qb][4 wv] (2KB) | mpack[64][16] (4KB)

__global__ void prep_kernel(const float* __restrict__ Wx,
                            const float* __restrict__ Wr,
                            const float* __restrict__ init_h,
                            const int*   __restrict__ mask,
                            unsigned short* __restrict__ WB,
                            unsigned* __restrict__ hbuf0,
                            unsigned* __restrict__ flags,
                            unsigned* __restrict__ mpack) {
    int idx = blockIdx.x * blockDim.x + threadIdx.x;
    if (idx < GG * KK) {                 // WB[g][k] = W[k][g], bf16
        int g = idx >> 10, k = idx & 1023;
        float v = (k < DD) ? Wx[(size_t)k * GG + g]
                           : Wr[(size_t)(k - DD) * GG + g];
        WB[idx] = f2bf(v);
    }
    if (idx < BB * HH / 2) {             // h0 pairs into [grp][buf0][row][256]
        int b = idx >> 8, p = idx & 255;
        unsigned lo = f2bf(init_h[b * HH + 2 * p]);
        unsigned hi = f2bf(init_h[b * HH + 2 * p + 1]);
        hbuf0[(b >> 3) * 4096 + (b & 7) * 256 + p] = lo | (hi << 16);
    }
    if (idx < 512) flags[idx] = 0u;
    if (idx < 64 * 16) {
        int b = idx >> 4, w = idx & 15;
        unsigned word = 0u;
        for (int tb = 0; tb < 32; ++tb)
            word |= (mask[b * TT + w * 32 + tb] != 0 ? 1u : 0u) << tb;
        mpack[idx] = word;
    }
}

__global__ void __launch_bounds__(NTHR, 1)
lstm_kernel(const float* __restrict__ x,
            const unsigned short* __restrict__ WB,
            const float* __restrict__ bias,
            unsigned*    hbuf,                    // sc1-only traffic
            unsigned*    flags,                   // sc1-only, [grp][qb][wv]
            const unsigned* __restrict__ mpack,
            const float* __restrict__ init_h,
            const float* __restrict__ init_c,
            float* __restrict__ out)
{
    extern __shared__ char smem[];
    char*     smx   = smem;                       // x A-tile [8][1024B] swz
    char*     smh   = smem + 8192;                // h A-tile [8][1024B] swz
    float*    zlp   = (float*)(smem + 16384);     // [2 kh][8 rows][129]
    unsigned* m_lds = (unsigned*)(smem + 16384 + LDS_ZL);  // [8][16]

    const int tid = threadIdx.x;
    const int bid = blockIdx.x;
    const int w   = tid >> 6;          // wave 0..7
    const int l   = tid & 63;
    const int kh  = w >> 2;            // k-half 0/1
    const int ng  = w & 3;             // n-group: n-tiles 2ng, 2ng+1

    const int grp    = bid & 7;        // batch octet: rows grp*8..+7
    const int qb     = bid >> 3;       // j-slice 0..15
    const int j_base = qb * 32;
    const int obase  = grp * 8;

    // ---- persistent B-fragments: (8x + 8h ktiles) x 2 n-tiles (128 VGPR) ----
    short8 bf[16][2];
    #pragma unroll
    for (int nt = 0; nt < 2; ++nt) {
        int n   = ng * 2 + nt;
        int col = n * 16 + (l & 15);                   // 0..127
        int g   = (col >> 5) * 512 + j_base + (col & 31);
        const unsigned short* wrow = WB + (size_t)g * KK + (l >> 4) * 8;
        #pragma unroll
        for (int i = 0; i < 8; ++i) {
            bf[i][nt]     = *(const short8*)(wrow + (kh * 8 + i) * 32);
            bf[8 + i][nt] = *(const short8*)(wrow + (16 + kh * 8 + i) * 32);
        }
    }

    // ---- update mapping (tid < 256): one (row, j) each ----
    const int m_u = tid >> 5, jl = tid & 31;           // m_u 0..7, jl 0..31
    const int b_glob = obase + m_u;
    const int jg = j_base + jl;
    float c_reg = 0.f, h_reg = 0.f, po_reg = 0.f;
    float bias_r[4] = {0.f, 0.f, 0.f, 0.f};
    if (tid < 256) {
        c_reg = init_c[b_glob * HH + jg];
        h_reg = init_h[b_glob * HH + jg];
        #pragma unroll
        for (int gt = 0; gt < 4; ++gt) bias_r[gt] = bias[gt * 512 + jg];
    }
    for (int i = tid; i < 128; i += NTHR)
        m_lds[i] = mpack[(obase + (i >> 4)) * 16 + (i & 15)];

    unsigned* hgrp = hbuf + grp * 4096;                // [2][8][256]
    const size_t OUT_HF = (size_t)BB * TT * HH;
    const size_t OUT_CF = OUT_HF + (size_t)BB * HH;
    const int arow = l & 7;            // A row (lanes 8-15 duplicate rows 0-7)
    const int rsw  = arow << 4;
    const int xrow_s = tid >> 6;       // staging slot: row, col
    const int xcol_s = tid & 63;

    // ---- prologue: stage x[0] (512 threads, 1 short8 each) ----
    {
        const float4* xp = (const float4*)(
            x + ((size_t)(obase + xrow_s) * TT + 0) * DD + 8 * xcol_s);
        float4 f0 = xp[0], f1 = xp[1];
        short8 v;
        v[0] = (short)f2bf(f0.x); v[1] = (short)f2bf(f0.y);
        v[2] = (short)f2bf(f0.z); v[3] = (short)f2bf(f0.w);
        v[4] = (short)f2bf(f1.x); v[5] = (short)f2bf(f1.y);
        v[6] = (short)f2bf(f1.z); v[7] = (short)f2bf(f1.w);
        *(short8*)(smx + xrow_s * 1024 +
                   ((16 * xcol_s) ^ ((xrow_s & 7) << 4))) = v;
    }
    __syncthreads();

    for (int t = 0; t < TT; ++t) {
        // ---- (1) poll 64 per-wave flags: 1 dword/lane, 4 lines ----
        {
            const unsigned tgt = (unsigned)t;
            const unsigned* fb = flags + grp * 64;
            for (;;) {
                unsigned v = __hip_atomic_load(fb + l, __ATOMIC_RELAXED,
                                               __HIP_MEMORY_SCOPE_AGENT);
                if (__all(v >= tgt)) break;
                __builtin_amdgcn_s_sleep(1);
            }
        }

        // ---- (2) issue h row load (sc1) + x[t+1] prefetch (cached) ----
        const unsigned* curb = hgrp + (size_t)(t & 1) * 2048;
        unsigned*       nxtb = hgrp + (size_t)((t + 1) & 1) * 2048;
        uint4 hv, xv0, xv1;
        {
            const unsigned* hp = curb + w * 256 + l * 4;
            asm volatile("global_load_dwordx4 %0, %1, off sc1"
                         : "=v"(hv) : "v"(hp) : "memory");
        }
        if (t + 1 < TT) {
            const float* xrp = x + ((size_t)(obase + xrow_s) * TT + (t + 1)) * DD
                                 + 8 * xcol_s;
            asm volatile("global_load_dwordx4 %0, %2, off\n\t"
                         "global_load_dwordx4 %1, %3, off"
                         : "=&v"(xv0), "=&v"(xv1)
                         : "v"(xrp), "v"(xrp + 4) : "memory");
        }

        // ---- (3) 16 x-MFMAs hide the load latency ----
        f32x4 acc0 = {0.f, 0.f, 0.f, 0.f}, acc1 = {0.f, 0.f, 0.f, 0.f};
        #pragma unroll
        for (int i = 0; i < 8; ++i) {
            int kt = kh * 8 + i;
            short8 a = *(const short8*)(
                smx + arow * 1024 + ((kt * 64 + (l >> 4) * 16) ^ rsw));
            acc0 = __builtin_amdgcn_mfma_f32_16x16x32_bf16(a, bf[i][0], acc0, 0, 0, 0);
            acc1 = __builtin_amdgcn_mfma_f32_16x16x32_bf16(a, bf[i][1], acc1, 0, 0, 0);
        }

        // ---- (4) wait h (x still in flight), stage smh ----
        if (t + 1 < TT) asm volatile("s_waitcnt vmcnt(2)" ::: "memory");
        else            asm volatile("s_waitcnt vmcnt(0)" ::: "memory");
        __builtin_amdgcn_sched_barrier(0);
        {
            union { uint4 u; short8 s; } cv; cv.u = hv;
            *(short8*)(smh + w * 1024 + ((l * 16) ^ ((w & 7) << 4))) = cv.s;
        }
        __syncthreads();   // bar A: smh ready; smx(t) reads done

        // ---- (5) 16 h-MFMAs + zl write (2 partials, 2-way-free banks) ----
        #pragma unroll
        for (int i = 0; i < 8; ++i) {
            int kt = kh * 8 + i;
            short8 a = *(const short8*)(
                smh + arow * 1024 + ((kt * 64 + (l >> 4) * 16) ^ rsw));
            acc0 = __builtin_amdgcn_mfma_f32_16x16x32_bf16(a, bf[8 + i][0], acc0, 0, 0, 0);
            acc1 = __builtin_amdgcn_mfma_f32_16x16x32_bf16(a, bf[8 + i][1], acc1, 0, 0, 0);
        }
        if ((l >> 4) < 2) {
            #pragma unroll
            for (int r = 0; r < 4; ++r) {
                int row = (l >> 4) * 4 + r;            // 0..7
                zlp[(kh * 8 + row) * 129 + (ng * 2) * 16 + (l & 15)]     = acc0[r];
                zlp[(kh * 8 + row) * 129 + (ng * 2 + 1) * 16 + (l & 15)] = acc1[r];
            }
        }

        // ---- (6) x[t+1] -> smx (reads for t finished pre-barA) ----
        if (t + 1 < TT) {
            asm volatile("s_waitcnt vmcnt(0)" ::: "memory");
            __builtin_amdgcn_sched_barrier(0);
            union { uint4 u; float4 f; } xa, xb; xa.u = xv0; xb.u = xv1;
            unsigned u0, u1, u2, u3;
            asm("v_cvt_pk_bf16_f32 %0, %1, %2" : "=v"(u0) : "v"(xa.f.x), "v"(xa.f.y));
            asm("v_cvt_pk_bf16_f32 %0, %1, %2" : "=v"(u1) : "v"(xa.f.z), "v"(xa.f.w));
            asm("v_cvt_pk_bf16_f32 %0, %1, %2" : "=v"(u2) : "v"(xb.f.x), "v"(xb.f.y));
            asm("v_cvt_pk_bf16_f32 %0, %1, %2" : "=v"(u3) : "v"(xb.f.z), "v"(xb.f.w));
            union { unsigned u[4]; short8 s; } cv;
            cv.u[0] = u0; cv.u[1] = u1; cv.u[2] = u2; cv.u[3] = u3;
            *(short8*)(smx + xrow_s * 1024 +
                       ((16 * xcol_s) ^ ((xrow_s & 7) << 4))) = cv.s;
        }
        __syncthreads();   // bar B: zl + smx(t+1) ready

        // ---- (7) update (waves 0-3); waves 4-7 roll to poll(t+1) ----
        if (tid < 256) {
            const int wv = tid >> 6;                   // update wave 0..3
            bool msk = ((m_lds[m_u * 16 + (t >> 5)] >> (t & 31)) & 1u) != 0u;
            float z[4];
            #pragma unroll
            for (int gt = 0; gt < 4; ++gt)
                z[gt] = bias_r[gt]
                      + zlp[m_u * 129 + gt * 32 + jl]
                      + zlp[(8 + m_u) * 129 + gt * 32 + jl];
            float ig = fsig(z[0]);
            float fg = fsig(z[1]);
            float gg = ftanh_(z[2]);
            float og = fsig(z[3]);
            float c_new = fg * c_reg + ig * gg;
            float h_new = og * ftanh_(c_new);
            float ov = msk ? h_new : po_reg;
            float h2 = msk ? h_new : h_reg;
            float c2 = msk ? c_new : c_reg;
            out[((size_t)b_glob * TT + t) * HH + jg] = ov;
            float hp1 = __shfl_xor(h2, 1);             // partner j's h
            if ((jl & 1) == 0) {
                unsigned pv = (unsigned)f2bf(h2) | ((unsigned)f2bf(hp1) << 16);
                unsigned* hp = nxtb + m_u * 256 + qb * 16 + (jl >> 1);
                asm volatile("global_store_dword %0, %1, off sc1"
                             :: "v"(hp), "v"(pv) : "memory");
            }
            c_reg = c2; h_reg = h2; po_reg = ov;
            // own-wave drain, then own-wave flag: no block barrier needed
            asm volatile("s_waitcnt vmcnt(0)" ::: "memory");
            if (l == 0) {
                unsigned* fp = flags + grp * 64 + qb * 4 + wv;
                unsigned fv = (unsigned)(t + 1);
                asm volatile("global_store_dword %0, %1, off sc1"
                             :: "v"(fp), "v"(fv) : "memory");
            }
        }
    }

    if (tid < 256) {
        out[OUT_HF + (size_t)b_glob * HH + jg] = h_reg;
        out[OUT_CF + (size_t)b_glob * HH + jg] = c_reg;
    }
}

extern "C" void kernel_launch(void* const* d_in, const int* in_sizes, int n_in,
                              void* d_out, int out_size, void* d_ws, size_t ws_size,
                              hipStream_t stream) {
    const float* x      = (const float*)d_in[0];
    const float* init_h = (const float*)d_in[1];
    const float* init_c = (const float*)d_in[2];
    const float* Wx     = (const float*)d_in[3];
    const float* Wr     = (const float*)d_in[4];
    const float* bias   = (const float*)d_in[5];
    const int*   mask   = (const int*)d_in[6];
    float* out = (float*)d_out;

    unsigned short* WB    = (unsigned short*)d_ws;              // 4 MB
    unsigned*       hbuf  = (unsigned*)(WB + (size_t)GG * KK);  // 128 KB
    unsigned*       flags = hbuf + 8 * 4096;                    // 2 KB
    unsigned*       mpack = flags + 512;                        // 4 KB

    prep_kernel<<<(GG * KK + 255) / 256, 256, 0, stream>>>(
        Wx, Wr, init_h, mask, WB, hbuf, flags, mpack);

    void* args[] = { (void*)&x, (void*)&WB, (void*)&bias, (void*)&hbuf,
                     (void*)&flags, (void*)&mpack, (void*)&init_h,
                     (void*)&init_c, (void*)&out };
    (void)hipLaunchCooperativeKernel((const void*)lstm_kernel, dim3(NBLK),
                                     dim3(NTHR), args, (unsigned)LDS_BYTES,
                                     stream);
}

// Round 16
// 1381.771 us; speedup vs baseline: 2.4898x; 2.4898x over previous
//
#include <hip/hip_runtime.h>

constexpr int BB = 64, TT = 512, DD = 512, HH = 512;
constexpr int GG = 4 * HH;          // 2048 gate cols
constexpr int KK = DD + HH;         // 1024 fused K
constexpr int NBLK = 128, NTHR = 512;
// LDS: xA[8][1024B] | hA[8][1024B] | zl[4][16][129] f32 | mask[8][16]
constexpr int LDS_ZL = 4 * 16 * 129 * 4;
constexpr int LDS_BYTES = 8192 + 8192 + LDS_ZL + 512;

using short8 = __attribute__((ext_vector_type(8))) short;
using f32x4  = __attribute__((ext_vector_type(4))) float;

__device__ __host__ __forceinline__ unsigned short f2bf(float f) {
    union { float f; unsigned u; } v; v.f = f;
    unsigned u = v.u + 0x7fffu + ((v.u >> 16) & 1u);   // RNE
    return (unsigned short)(u >> 16);
}
__device__ __forceinline__ float fsig(float x) {
    return 1.f / (1.f + __expf(-x));
}
__device__ __forceinline__ float ftanh_(float x) {
    float e = __expf(2.f * fabsf(x));
    float r = 1.f - 2.f / (e + 1.f);
    return copysignf(r, x);
}

// ws: WB[2048][1024] bf16 (4MB) | hbuf[8 grp][2][8][256] u32 (128KB)
//     | flags[8 grp][16][16pad] (8KB) | mpack[64][16] (4KB)

__global__ void prep_kernel(const float* __restrict__ Wx,
                            const float* __restrict__ Wr,
                            const float* __restrict__ init_h,
                            const int*   __restrict__ mask,
                            unsigned short* __restrict__ WB,
                            unsigned* __restrict__ hbuf0,
                            unsigned* __restrict__ flags,
                            unsigned* __restrict__ mpack) {
    int idx = blockIdx.x * blockDim.x + threadIdx.x;
    if (idx < GG * KK) {                 // WB[g][k] = W[k][g], bf16
        int g = idx >> 10, k = idx & 1023;
        float v = (k < DD) ? Wx[(size_t)k * GG + g]
                           : Wr[(size_t)(k - DD) * GG + g];
        WB[idx] = f2bf(v);
    }
    if (idx < BB * HH / 2) {             // h0 pairs into [grp][buf0][row][256]
        int b = idx >> 8, p = idx & 255;
        unsigned lo = f2bf(init_h[b * HH + 2 * p]);
        unsigned hi = f2bf(init_h[b * HH + 2 * p + 1]);
        hbuf0[(b >> 3) * 4096 + (b & 7) * 256 + p] = lo | (hi << 16);
    }
    if (idx < 2048) flags[idx] = 0u;
    if (idx < 64 * 16) {
        int b = idx >> 4, w = idx & 15;
        unsigned word = 0u;
        for (int tb = 0; tb < 32; ++tb)
            word |= (mask[b * TT + w * 32 + tb] != 0 ? 1u : 0u) << tb;
        mpack[idx] = word;
    }
}

__global__ void __launch_bounds__(NTHR, 1)
lstm_kernel(const float* __restrict__ x,
            const unsigned short* __restrict__ WB,
            const float* __restrict__ bias,
            unsigned*    hbuf,                    // sc1-only traffic
            unsigned*    flags,                   // sc1-only, line-padded
            const unsigned* __restrict__ mpack,
            const float* __restrict__ init_h,
            const float* __restrict__ init_c,
            float* __restrict__ out)
{
    extern __shared__ char smem[];
    char*     smx   = smem;                       // x A-tile [8][1024B] swz
    char*     smh   = smem + 8192;                // h A-tile [8][1024B] swz
    float*    zlp   = (float*)(smem + 16384);     // [4][16][129]
    unsigned* m_lds = (unsigned*)(smem + 16384 + LDS_ZL);  // [8][16]

    const int tid = threadIdx.x;
    const int bid = blockIdx.x;
    const int w   = tid >> 6;          // wave 0..7
    const int l   = tid & 63;
    const int kq  = w >> 1;            // k-quarter 0..3
    const int nh  = w & 1;             // n-half: n-tiles 4nh..4nh+3

    // static groups: grp = bid&7 (round-robin -> co-XCD tendency, not relied on)
    const int grp    = bid & 7;        // batch octet: rows grp*8..+7
    const int qb     = bid >> 3;       // j-slice 0..15
    const int j_base = qb * 32;
    const int obase  = grp * 8;

    // ---- persistent B-fragments: 8 ktiles x 4 n-tiles (128 VGPR) ----
    short8 bf[8][4];
    #pragma unroll
    for (int nt = 0; nt < 4; ++nt) {
        int n   = nh * 4 + nt;
        int col = n * 16 + (l & 15);                   // 0..127
        int g   = (col >> 5) * 512 + j_base + (col & 31);
        const unsigned short* wrow = WB + (size_t)g * KK + (l >> 4) * 8;
        #pragma unroll
        for (int i = 0; i < 4; ++i) {
            bf[i][nt]     = *(const short8*)(wrow + (kq * 4 + i) * 32);
            bf[4 + i][nt] = *(const short8*)(wrow + (16 + kq * 4 + i) * 32);
        }
    }

    // ---- update mapping (tid < 256): one (row, j) each ----
    const int m_u = tid >> 5, jl = tid & 31;           // m_u 0..7, jl 0..31
    const int b_glob = obase + m_u;
    const int jg = j_base + jl;
    float c_reg = 0.f, h_reg = 0.f, po_reg = 0.f;
    float bias_r[4] = {0.f, 0.f, 0.f, 0.f};
    if (tid < 256) {
        c_reg = init_c[b_glob * HH + jg];
        h_reg = init_h[b_glob * HH + jg];
        #pragma unroll
        for (int gt = 0; gt < 4; ++gt) bias_r[gt] = bias[gt * 512 + jg];
    }
    for (int i = tid; i < 128; i += NTHR)
        m_lds[i] = mpack[(obase + (i >> 4)) * 16 + (i & 15)];

    unsigned* hgrp = hbuf + grp * 4096;                // [2][8][256]
    const size_t OUT_HF = (size_t)BB * TT * HH;
    const size_t OUT_CF = OUT_HF + (size_t)BB * HH;
    const int arow = l & 7;            // A row (lanes 8-15 duplicate rows 0-7)
    const int rsw  = arow << 4;

    // ---- prologue: stage x[0] ----
    for (int u = tid; u < 512; u += NTHR) {
        int row = u >> 6, c = u & 63;
        const float4* xp = (const float4*)(
            x + ((size_t)(obase + row) * TT + 0) * DD + 8 * c);
        float4 f0 = xp[0], f1 = xp[1];
        short8 v;
        v[0] = (short)f2bf(f0.x); v[1] = (short)f2bf(f0.y);
        v[2] = (short)f2bf(f0.z); v[3] = (short)f2bf(f0.w);
        v[4] = (short)f2bf(f1.x); v[5] = (short)f2bf(f1.y);
        v[6] = (short)f2bf(f1.z); v[7] = (short)f2bf(f1.w);
        *(short8*)(smx + row * 1024 + ((16 * c) ^ ((row & 7) << 4))) = v;
    }
    __syncthreads();

    for (int t = 0; t < TT; ++t) {
        // ---- (1) poll own group's 16 line-padded flags (all waves) ----
        {
            const unsigned tgt = (unsigned)t;
            const unsigned* fb = flags + grp * 256 + (l & 15) * 16;
            for (;;) {
                unsigned v = __hip_atomic_load(fb, __ATOMIC_RELAXED,
                                               __HIP_MEMORY_SCOPE_AGENT);
                if (__all(v >= tgt)) break;
                __builtin_amdgcn_s_sleep(1);
            }
        }

        // ---- (2) issue h row load: wave w -> row w (1KB, coalesced sc1) ----
        const unsigned* curb = hgrp + (size_t)(t & 1) * 2048;
        unsigned*       nxtb = hgrp + (size_t)((t + 1) & 1) * 2048;
        uint4 hv;
        {
            const unsigned* hp = curb + w * 256 + l * 4;
            asm volatile("global_load_dwordx4 %0, %1, off sc1"
                         : "=v"(hv) : "v"(hp) : "memory");
        }

        // ---- (3) x-MFMAs (LDS staged in prev tail) hide h-load latency ----
        f32x4 acc[4] = {{0,0,0,0},{0,0,0,0},{0,0,0,0},{0,0,0,0}};
        #pragma unroll
        for (int i = 0; i < 4; ++i) {
            int kt = kq * 4 + i;
            short8 a = *(const short8*)(
                smx + arow * 1024 + ((kt * 64 + (l >> 4) * 16) ^ rsw));
            #pragma unroll
            for (int nt = 0; nt < 4; ++nt)
                acc[nt] = __builtin_amdgcn_mfma_f32_16x16x32_bf16(a, bf[i][nt], acc[nt], 0, 0, 0);
        }

        // ---- (4) wait h, stage into LDS ----
        asm volatile("s_waitcnt vmcnt(0)" ::: "memory");
        __builtin_amdgcn_sched_barrier(0);
        {
            union { uint4 u; short8 s; } cv; cv.u = hv;
            *(short8*)(smh + w * 1024 + ((l * 16) ^ ((w & 7) << 4))) = cv.s;
        }
        __syncthreads();   // bar A: smh ready

        // ---- (5) h-MFMAs + zl write (live rows 0-7 only) ----
        #pragma unroll
        for (int i = 0; i < 4; ++i) {
            int kt = kq * 4 + i;
            short8 a = *(const short8*)(
                smh + arow * 1024 + ((kt * 64 + (l >> 4) * 16) ^ rsw));
            #pragma unroll
            for (int nt = 0; nt < 4; ++nt)
                acc[nt] = __builtin_amdgcn_mfma_f32_16x16x32_bf16(a, bf[4 + i][nt], acc[nt], 0, 0, 0);
        }
        if ((l >> 4) < 2) {
            #pragma unroll
            for (int nt = 0; nt < 4; ++nt) {
                int n = nh * 4 + nt;
                #pragma unroll
                for (int r = 0; r < 4; ++r) {
                    int m = (l >> 4) * 4 + r;      // 0..7
                    zlp[(kq * 16 + m) * 129 + n * 16 + (l & 15)] = acc[nt][r];
                }
            }
        }
        __syncthreads();   // bar B: zl ready

        // ---- (6) update (waves 0-3) || stage x[t+1] (waves 4-7) ----
        if (tid < 256) {
            bool msk = ((m_lds[m_u * 16 + (t >> 5)] >> (t & 31)) & 1u) != 0u;
            float z[4];
            #pragma unroll
            for (int gt = 0; gt < 4; ++gt) {
                float s = bias_r[gt];
                #pragma unroll
                for (int p = 0; p < 4; ++p)
                    s += zlp[(p * 16 + m_u) * 129 + gt * 32 + jl];
                z[gt] = s;
            }
            float ig = fsig(z[0]);
            float fg = fsig(z[1]);
            float gg = ftanh_(z[2]);
            float og = fsig(z[3]);
            float c_new = fg * c_reg + ig * gg;
            float h_new = og * ftanh_(c_new);
            float ov = msk ? h_new : po_reg;
            float h2 = msk ? h_new : h_reg;
            float c2 = msk ? c_new : c_reg;
            out[((size_t)b_glob * TT + t) * HH + jg] = ov;
            unsigned hb16 = f2bf(h2);
            unsigned other = (unsigned)__shfl_xor((int)hb16, 1);
            if ((jl & 1) == 0)
                __hip_atomic_store(nxtb + m_u * 256 + qb * 16 + (jl >> 1),
                                   hb16 | (other << 16), __ATOMIC_RELAXED,
                                   __HIP_MEMORY_SCOPE_AGENT);
            c_reg = c2; h_reg = h2; po_reg = ov;
        } else if (t + 1 < TT) {
            for (int u = tid - 256; u < 512; u += 256) {
                int row = u >> 6, c = u & 63;
                const float4* xp = (const float4*)(
                    x + ((size_t)(obase + row) * TT + (t + 1)) * DD + 8 * c);
                float4 f0 = xp[0], f1 = xp[1];
                short8 v;
                v[0] = (short)f2bf(f0.x); v[1] = (short)f2bf(f0.y);
                v[2] = (short)f2bf(f0.z); v[3] = (short)f2bf(f0.w);
                v[4] = (short)f2bf(f1.x); v[5] = (short)f2bf(f1.y);
                v[6] = (short)f2bf(f1.z); v[7] = (short)f2bf(f1.w);
                *(short8*)(smx + row * 1024 + ((16 * c) ^ ((row & 7) << 4))) = v;
            }
        }
        // bar C: per-wave vmcnt drain -> h sc1-stores at coherence point
        // before the flag store; also: smx staged, zl consumed.
        __syncthreads();

        if (tid == 0)
            __hip_atomic_store(flags + (grp * 16 + qb) * 16, (unsigned)(t + 1),
                               __ATOMIC_RELAXED, __HIP_MEMORY_SCOPE_AGENT);
    }

    if (tid < 256) {
        out[OUT_HF + (size_t)b_glob * HH + jg] = h_reg;
        out[OUT_CF + (size_t)b_glob * HH + jg] = c_reg;
    }
}

extern "C" void kernel_launch(void* const* d_in, const int* in_sizes, int n_in,
                              void* d_out, int out_size, void* d_ws, size_t ws_size,
                              hipStream_t stream) {
    const float* x      = (const float*)d_in[0];
    const float* init_h = (const float*)d_in[1];
    const float* init_c = (const float*)d_in[2];
    const float* Wx     = (const float*)d_in[3];
    const float* Wr     = (const float*)d_in[4];
    const float* bias   = (const float*)d_in[5];
    const int*   mask   = (const int*)d_in[6];
    float* out = (float*)d_out;

    unsigned short* WB    = (unsigned short*)d_ws;              // 4 MB
    unsigned*       hbuf  = (unsigned*)(WB + (size_t)GG * KK);  // 128 KB
    unsigned*       flags = hbuf + 8 * 4096;                    // 8 KB
    unsigned*       mpack = flags + 2048;                       // 4 KB

    prep_kernel<<<(GG * KK + 255) / 256, 256, 0, stream>>>(
        Wx, Wr, init_h, mask, WB, hbuf, flags, mpack);

    void* args[] = { (void*)&x, (void*)&WB, (void*)&bias, (void*)&hbuf,
                     (void*)&flags, (void*)&mpack, (void*)&init_h,
                     (void*)&init_c, (void*)&out };
    (void)hipLaunchCooperativeKernel((const void*)lstm_kernel, dim3(NBLK),
                                     dim3(NTHR), args, (unsigned)LDS_BYTES,
                                     stream);
}

// Round 17
// 1376.566 us; speedup vs baseline: 2.4992x; 1.0038x over previous
//
#include <hip/hip_runtime.h>

constexpr int BB = 64, TT = 512, DD = 512, HH = 512;
constexpr int GG = 4 * HH;          // 2048 gate cols
constexpr int KK = DD + HH;         // 1024 fused K
constexpr int NBLK = 128, NTHR = 512;
// LDS: xA[8][1024B] | hA[8][1024B] | zl[4][16][129] f32 | mask[8][16]
constexpr int LDS_ZL = 4 * 16 * 129 * 4;
constexpr int LDS_BYTES = 8192 + 8192 + LDS_ZL + 512;

using short8 = __attribute__((ext_vector_type(8))) short;
using f32x4  = __attribute__((ext_vector_type(4))) float;

__device__ __host__ __forceinline__ unsigned short f2bf(float f) {
    union { float f; unsigned u; } v; v.f = f;
    unsigned u = v.u + 0x7fffu + ((v.u >> 16) & 1u);   // RNE
    return (unsigned short)(u >> 16);
}
__device__ __forceinline__ float fsig(float x) {
    return 1.f / (1.f + __expf(-x));
}
__device__ __forceinline__ float ftanh_(float x) {
    float e = __expf(2.f * fabsf(x));
    float r = 1.f - 2.f / (e + 1.f);
    return copysignf(r, x);
}

// ws: WB[2048][1024] bf16 (4MB) | hbuf[8 grp][2][8][256] u32 (128KB)
//     | flags[8 grp][16][16pad] (8KB) | mpack[64][16] (4KB)

__global__ void prep_kernel(const float* __restrict__ Wx,
                            const float* __restrict__ Wr,
                            const float* __restrict__ init_h,
                            const int*   __restrict__ mask,
                            unsigned short* __restrict__ WB,
                            unsigned* __restrict__ hbuf0,
                            unsigned* __restrict__ flags,
                            unsigned* __restrict__ mpack) {
    int idx = blockIdx.x * blockDim.x + threadIdx.x;
    if (idx < GG * KK) {                 // WB[g][k] = W[k][g], bf16
        int g = idx >> 10, k = idx & 1023;
        float v = (k < DD) ? Wx[(size_t)k * GG + g]
                           : Wr[(size_t)(k - DD) * GG + g];
        WB[idx] = f2bf(v);
    }
    if (idx < BB * HH / 2) {             // h0 pairs into [grp][buf0][row][256]
        int b = idx >> 8, p = idx & 255;
        unsigned lo = f2bf(init_h[b * HH + 2 * p]);
        unsigned hi = f2bf(init_h[b * HH + 2 * p + 1]);
        hbuf0[(b >> 3) * 4096 + (b & 7) * 256 + p] = lo | (hi << 16);
    }
    if (idx < 2048) flags[idx] = 0u;
    if (idx < 64 * 16) {
        int b = idx >> 4, w = idx & 15;
        unsigned word = 0u;
        for (int tb = 0; tb < 32; ++tb)
            word |= (mask[b * TT + w * 32 + tb] != 0 ? 1u : 0u) << tb;
        mpack[idx] = word;
    }
}

__global__ void __launch_bounds__(NTHR, 1)
lstm_kernel(const float* __restrict__ x,
            const unsigned short* __restrict__ WB,
            const float* __restrict__ bias,
            unsigned*    hbuf,                    // sc1-only traffic
            unsigned*    flags,                   // sc1-only, line-padded
            const unsigned* __restrict__ mpack,
            const float* __restrict__ init_h,
            const float* __restrict__ init_c,
            float* __restrict__ out)
{
    extern __shared__ char smem[];
    char*     smx   = smem;                       // x A-tile [8][1024B] swz
    char*     smh   = smem + 8192;                // h A-tile [8][1024B] swz
    float*    zlp   = (float*)(smem + 16384);     // [4][16][129]
    unsigned* m_lds = (unsigned*)(smem + 16384 + LDS_ZL);  // [8][16]

    const int tid = threadIdx.x;
    const int bid = blockIdx.x;
    const int w   = tid >> 6;          // wave 0..7
    const int l   = tid & 63;
    const int kq  = w >> 1;            // k-quarter 0..3
    const int nh  = w & 1;             // n-half: n-tiles 4nh..4nh+3

    // static groups: grp = bid&7 (round-robin -> co-XCD tendency, not relied on)
    const int grp    = bid & 7;        // batch octet: rows grp*8..+7
    const int qb     = bid >> 3;       // j-slice 0..15
    const int j_base = qb * 32;
    const int obase  = grp * 8;

    // ---- persistent B-fragments: 8 ktiles x 4 n-tiles (128 VGPR) ----
    short8 bf[8][4];
    #pragma unroll
    for (int nt = 0; nt < 4; ++nt) {
        int n   = nh * 4 + nt;
        int col = n * 16 + (l & 15);                   // 0..127
        int g   = (col >> 5) * 512 + j_base + (col & 31);
        const unsigned short* wrow = WB + (size_t)g * KK + (l >> 4) * 8;
        #pragma unroll
        for (int i = 0; i < 4; ++i) {
            bf[i][nt]     = *(const short8*)(wrow + (kq * 4 + i) * 32);
            bf[4 + i][nt] = *(const short8*)(wrow + (16 + kq * 4 + i) * 32);
        }
    }

    // ---- update mapping (tid < 256): one (row, j) each ----
    const int m_u = tid >> 5, jl = tid & 31;           // m_u 0..7, jl 0..31
    const int b_glob = obase + m_u;
    const int jg = j_base + jl;
    float c_reg = 0.f, h_reg = 0.f, po_reg = 0.f;
    float bias_r[4] = {0.f, 0.f, 0.f, 0.f};
    if (tid < 256) {
        c_reg = init_c[b_glob * HH + jg];
        h_reg = init_h[b_glob * HH + jg];
        #pragma unroll
        for (int gt = 0; gt < 4; ++gt) bias_r[gt] = bias[gt * 512 + jg];
    }
    for (int i = tid; i < 128; i += NTHR)
        m_lds[i] = mpack[(obase + (i >> 4)) * 16 + (i & 15)];

    unsigned* hgrp = hbuf + grp * 4096;                // [2][8][256]
    const size_t OUT_HF = (size_t)BB * TT * HH;
    const size_t OUT_CF = OUT_HF + (size_t)BB * HH;
    const int arow = l & 7;            // A row (lanes 8-15 duplicate rows 0-7)
    const int rsw  = arow << 4;

    // ---- prologue: stage x[0] ----
    for (int u = tid; u < 512; u += NTHR) {
        int row = u >> 6, c = u & 63;
        const float4* xp = (const float4*)(
            x + ((size_t)(obase + row) * TT + 0) * DD + 8 * c);
        float4 f0 = xp[0], f1 = xp[1];
        short8 v;
        v[0] = (short)f2bf(f0.x); v[1] = (short)f2bf(f0.y);
        v[2] = (short)f2bf(f0.z); v[3] = (short)f2bf(f0.w);
        v[4] = (short)f2bf(f1.x); v[5] = (short)f2bf(f1.y);
        v[6] = (short)f2bf(f1.z); v[7] = (short)f2bf(f1.w);
        *(short8*)(smx + row * 1024 + ((16 * c) ^ ((row & 7) << 4))) = v;
    }
    __syncthreads();

    for (int t = 0; t < TT; ++t) {
        // ---- (1) poll own group's 16 line-padded flags (all waves) ----
        {
            const unsigned tgt = (unsigned)t;
            const unsigned* fb = flags + grp * 256 + (l & 15) * 16;
            for (;;) {
                unsigned v = __hip_atomic_load(fb, __ATOMIC_RELAXED,
                                               __HIP_MEMORY_SCOPE_AGENT);
                if (__all(v >= tgt)) break;
                __builtin_amdgcn_s_sleep(1);
            }
        }

        // ---- (2) issue h row load: wave w -> row w (1KB, coalesced sc1) ----
        const unsigned* curb = hgrp + (size_t)(t & 1) * 2048;
        unsigned*       nxtb = hgrp + (size_t)((t + 1) & 1) * 2048;
        uint4 hv;
        {
            const unsigned* hp = curb + w * 256 + l * 4;
            asm volatile("global_load_dwordx4 %0, %1, off sc1"
                         : "=v"(hv) : "v"(hp) : "memory");
        }

        // ---- (3) x-MFMAs (LDS staged in prev tail) hide h-load latency ----
        f32x4 acc[4] = {{0,0,0,0},{0,0,0,0},{0,0,0,0},{0,0,0,0}};
        #pragma unroll
        for (int i = 0; i < 4; ++i) {
            int kt = kq * 4 + i;
            short8 a = *(const short8*)(
                smx + arow * 1024 + ((kt * 64 + (l >> 4) * 16) ^ rsw));
            #pragma unroll
            for (int nt = 0; nt < 4; ++nt)
                acc[nt] = __builtin_amdgcn_mfma_f32_16x16x32_bf16(a, bf[i][nt], acc[nt], 0, 0, 0);
        }

        // ---- (4) wait h, stage into LDS ----
        asm volatile("s_waitcnt vmcnt(0)" ::: "memory");
        __builtin_amdgcn_sched_barrier(0);
        {
            union { uint4 u; short8 s; } cv; cv.u = hv;
            *(short8*)(smh + w * 1024 + ((l * 16) ^ ((w & 7) << 4))) = cv.s;
        }
        __syncthreads();   // bar A: smh ready

        // ---- (5) h-MFMAs + zl write (live rows 0-7 only) ----
        #pragma unroll
        for (int i = 0; i < 4; ++i) {
            int kt = kq * 4 + i;
            short8 a = *(const short8*)(
                smh + arow * 1024 + ((kt * 64 + (l >> 4) * 16) ^ rsw));
            #pragma unroll
            for (int nt = 0; nt < 4; ++nt)
                acc[nt] = __builtin_amdgcn_mfma_f32_16x16x32_bf16(a, bf[4 + i][nt], acc[nt], 0, 0, 0);
        }
        if ((l >> 4) < 2) {
            #pragma unroll
            for (int nt = 0; nt < 4; ++nt) {
                int n = nh * 4 + nt;
                #pragma unroll
                for (int r = 0; r < 4; ++r) {
                    int m = (l >> 4) * 4 + r;      // 0..7
                    zlp[(kq * 16 + m) * 129 + n * 16 + (l & 15)] = acc[nt][r];
                }
            }
        }
        __syncthreads();   // bar B: zl ready

        // ---- (6) update (waves 0-3) || stage x[t+1] (waves 4-7) ----
        // out-store is DEFERRED past bar C: only h sc1-stores must precede
        // the flag; the out HBM write-ack completes under the next poll.
        float ov_keep = 0.f;
        if (tid < 256) {
            bool msk = ((m_lds[m_u * 16 + (t >> 5)] >> (t & 31)) & 1u) != 0u;
            float z[4];
            #pragma unroll
            for (int gt = 0; gt < 4; ++gt) {
                float s = bias_r[gt];
                #pragma unroll
                for (int p = 0; p < 4; ++p)
                    s += zlp[(p * 16 + m_u) * 129 + gt * 32 + jl];
                z[gt] = s;
            }
            float ig = fsig(z[0]);
            float fg = fsig(z[1]);
            float gg = ftanh_(z[2]);
            float og = fsig(z[3]);
            float c_new = fg * c_reg + ig * gg;
            float h_new = og * ftanh_(c_new);
            float ov = msk ? h_new : po_reg;
            float h2 = msk ? h_new : h_reg;
            float c2 = msk ? c_new : c_reg;
            unsigned hb16 = f2bf(h2);
            unsigned other = (unsigned)__shfl_xor((int)hb16, 1);
            if ((jl & 1) == 0)
                __hip_atomic_store(nxtb + m_u * 256 + qb * 16 + (jl >> 1),
                                   hb16 | (other << 16), __ATOMIC_RELAXED,
                                   __HIP_MEMORY_SCOPE_AGENT);
            c_reg = c2; h_reg = h2; po_reg = ov;
            ov_keep = ov;
        } else if (t + 1 < TT) {
            for (int u = tid - 256; u < 512; u += 256) {
                int row = u >> 6, c = u & 63;
                const float4* xp = (const float4*)(
                    x + ((size_t)(obase + row) * TT + (t + 1)) * DD + 8 * c);
                float4 f0 = xp[0], f1 = xp[1];
                short8 v;
                v[0] = (short)f2bf(f0.x); v[1] = (short)f2bf(f0.y);
                v[2] = (short)f2bf(f0.z); v[3] = (short)f2bf(f0.w);
                v[4] = (short)f2bf(f1.x); v[5] = (short)f2bf(f1.y);
                v[6] = (short)f2bf(f1.z); v[7] = (short)f2bf(f1.w);
                *(short8*)(smx + row * 1024 + ((16 * c) ^ ((row & 7) << 4))) = v;
            }
        }
        // bar C: per-wave vmcnt drain -> h sc1-stores at coherence point
        // before the flag store; also: smx staged, zl consumed.
        __syncthreads();

        if (tid == 0)
            __hip_atomic_store(flags + (grp * 16 + qb) * 16, (unsigned)(t + 1),
                               __ATOMIC_RELAXED, __HIP_MEMORY_SCOPE_AGENT);

        // deferred out-store: completes under the next iteration's poll/load
        if (tid < 256)
            out[((size_t)b_glob * TT + t) * HH + jg] = ov_keep;
    }

    if (tid < 256) {
        out[OUT_HF + (size_t)b_glob * HH + jg] = h_reg;
        out[OUT_CF + (size_t)b_glob * HH + jg] = c_reg;
    }
}

extern "C" void kernel_launch(void* const* d_in, const int* in_sizes, int n_in,
                              void* d_out, int out_size, void* d_ws, size_t ws_size,
                              hipStream_t stream) {
    const float* x      = (const float*)d_in[0];
    const float* init_h = (const float*)d_in[1];
    const float* init_c = (const float*)d_in[2];
    const float* Wx     = (const float*)d_in[3];
    const float* Wr     = (const float*)d_in[4];
    const float* bias   = (const float*)d_in[5];
    const int*   mask   = (const int*)d_in[6];
    float* out = (float*)d_out;

    unsigned short* WB    = (unsigned short*)d_ws;              // 4 MB
    unsigned*       hbuf  = (unsigned*)(WB + (size_t)GG * KK);  // 128 KB
    unsigned*       flags = hbuf + 8 * 4096;                    // 8 KB
    unsigned*       mpack = flags + 2048;                       // 4 KB

    prep_kernel<<<(GG * KK + 255) / 256, 256, 0, stream>>>(
        Wx, Wr, init_h, mask, WB, hbuf, flags, mpack);

    void* args[] = { (void*)&x, (void*)&WB, (void*)&bias, (void*)&hbuf,
                     (void*)&flags, (void*)&mpack, (void*)&init_h,
                     (void*)&init_c, (void*)&out };
    (void)hipLaunchCooperativeKernel((const void*)lstm_kernel, dim3(NBLK),
                                     dim3(NTHR), args, (unsigned)LDS_BYTES,
                                     stream);
}